// Round 8
// baseline (373.317 us; speedup 1.0000x reference)
//
#include <hip/hip_runtime.h>
#include <hip/hip_bf16.h>

// Problem constants (B=4, L=1024, D=1024, H=16, Dh=64, MAX_LEN=150)
#define BB 4
#define LL 1024
#define DD 1024
#define HH 16
#define DH 64
#define NPOS 301      // 2*MAX_LEN+1
#define MAXL 150
#define NEG_INF -1e30f

typedef __attribute__((ext_vector_type(4))) float f32x4;
typedef __attribute__((ext_vector_type(8))) short short8;

__device__ inline unsigned short f2b(float x) {
    __hip_bfloat16 h = __float2bfloat16(x);
    return *reinterpret_cast<unsigned short*>(&h);
}
__device__ inline unsigned pack2(float a, float b) {
    return (unsigned)f2b(a) | ((unsigned)f2b(b) << 16);
}
__device__ inline float b2f(unsigned short u) {
    return __uint_as_float((unsigned)u << 16);
}

// ---------------------------------------------------------------------------
// f32 -> bf16 conversion, 8 elems/thread
// ---------------------------------------------------------------------------
__global__ __launch_bounds__(256) void conv_b16(const float* __restrict__ in,
                                                unsigned short* __restrict__ out, int n)
{
    const size_t i = ((size_t)blockIdx.x * 256 + threadIdx.x) * 8;
    if (i >= (size_t)n) return;
    float4 a = *reinterpret_cast<const float4*>(in + i);
    float4 b = *reinterpret_cast<const float4*>(in + i + 4);
    ushort4 u0 = {f2b(a.x), f2b(a.y), f2b(a.z), f2b(a.w)};
    ushort4 u1 = {f2b(b.x), f2b(b.y), f2b(b.z), f2b(b.w)};
    *reinterpret_cast<ushort4*>(out + i) = u0;
    *reinterpret_cast<ushort4*>(out + i + 4) = u1;
}

// ---------------------------------------------------------------------------
// bf16 MFMA GEMM: C = (A @ W^T + bias) * oscale.  (validated round 7)
// Tile 128(M) x 64(N), BK=32, 4 waves (2x2), wave owns 64x32; padded-LDS
// reg-staged; fragment mapping validated rounds 6-7.
// EPI 0: f32 [M][N]                  (final projection)
// EPI 1: bf16 permuted [bh][l][dh]   (q/k projections)
// EPI 2: bf16 transposed [bh][dh][l] (v projection -> V^T direct)
// EPI 3: bf16 plain [M][N]           (qpos table, GN guards N=301)
// ---------------------------------------------------------------------------
template <int EPI, bool GN>
__global__ __launch_bounds__(256) void gemm_mfma(
    const unsigned short* __restrict__ A, const unsigned short* __restrict__ W,
    const float* __restrict__ bias, void* __restrict__ Cout,
    int M, int N, int K, float oscale)
{
    __shared__ alignas(16) unsigned short As[128 * 40];
    __shared__ alignas(16) unsigned short Bs[64 * 40];
    const int tid = threadIdx.x;
    const int w = tid >> 6, lane = tid & 63;
    const int wr = w >> 1, wc = w & 1;
    const int g = lane >> 4, fr = lane & 15;
    const int m0 = blockIdx.y * 128;
    const int n0 = blockIdx.x * 64;

    f32x4 acc[4][2];
#pragma unroll
    for (int i = 0; i < 4; ++i)
#pragma unroll
        for (int j = 0; j < 2; ++j) acc[i][j] = (f32x4){0.f, 0.f, 0.f, 0.f};

    const int arow0 = tid >> 2, agg = tid & 3;
    for (int k0 = 0; k0 < K; k0 += 32) {
        {
            short8 v0 = *reinterpret_cast<const short8*>(
                A + (size_t)(m0 + arow0) * K + k0 + agg * 8);
            short8 v1 = *reinterpret_cast<const short8*>(
                A + (size_t)(m0 + arow0 + 64) * K + k0 + agg * 8);
            int nr = n0 + arow0;
            if (GN && nr >= N) nr = N - 1;
            short8 bv = *reinterpret_cast<const short8*>(
                W + (size_t)nr * K + k0 + agg * 8);
            *reinterpret_cast<short8*>(&As[arow0 * 40 + agg * 8]) = v0;
            *reinterpret_cast<short8*>(&As[(arow0 + 64) * 40 + agg * 8]) = v1;
            *reinterpret_cast<short8*>(&Bs[arow0 * 40 + agg * 8]) = bv;
        }
        __syncthreads();
        short8 af[4], bf[2];
#pragma unroll
        for (int i = 0; i < 4; ++i)
            af[i] = *reinterpret_cast<const short8*>(
                &As[(wr * 64 + i * 16 + fr) * 40 + g * 8]);
#pragma unroll
        for (int j = 0; j < 2; ++j)
            bf[j] = *reinterpret_cast<const short8*>(
                &Bs[(wc * 32 + j * 16 + fr) * 40 + g * 8]);
#pragma unroll
        for (int i = 0; i < 4; ++i)
#pragma unroll
            for (int j = 0; j < 2; ++j)
                acc[i][j] = __builtin_amdgcn_mfma_f32_16x16x32_bf16(
                    af[i], bf[j], acc[i][j], 0, 0, 0);
        __syncthreads();
    }

#pragma unroll
    for (int i = 0; i < 4; ++i) {
#pragma unroll
        for (int j = 0; j < 2; ++j) {
#pragma unroll
            for (int r = 0; r < 4; ++r) {
                const int row = m0 + wr * 64 + i * 16 + g * 4 + r;
                const int col = n0 + wc * 32 + j * 16 + fr;
                if (GN && col >= N) continue;
                const float val = (acc[i][j][r] + (bias ? bias[col] : 0.f)) * oscale;
                if (EPI == 0) {
                    ((float*)Cout)[(size_t)row * N + col] = val;
                } else if (EPI == 1) {
                    const int b = row >> 10, l = row & 1023, hh = col >> 6, dh = col & 63;
                    ((unsigned short*)Cout)[(((size_t)(b * HH + hh)) * LL + l) * DH + dh] = f2b(val);
                } else if (EPI == 2) {
                    const int b = row >> 10, l = row & 1023, hh = col >> 6, dh = col & 63;
                    ((unsigned short*)Cout)[(((size_t)(b * HH + hh)) * DH + dh) * LL + l] = f2b(val);
                } else {
                    ((unsigned short*)Cout)[(size_t)row * N + col] = f2b(val);
                }
            }
        }
    }
}

// ---------------------------------------------------------------------------
// MFMA attention (structure validated rounds 6-7). Block = (bh, 64 q-rows);
// 4 waves x 16 q.  NEW this round: the block's 64 qpos rows (contiguous
// 64x301 bf16 = 38.5 KB) are bulk-staged into LDS with coalesced short8
// loads; the per-(q,k) relative-position gather then hits LDS (ds_read_u16)
// instead of issuing scalar cold-HBM loads (round 7: 256 such loads/lane,
// 79 MB of the 143 MB FETCH).
// ---------------------------------------------------------------------------
__global__ __launch_bounds__(256) void attn_mfma(
    const unsigned short* __restrict__ qbf,   // [bh][l][dh] bf16 (scaled 1/8)
    const unsigned short* __restrict__ kbf,   // [bh][l][dh] bf16
    const unsigned short* __restrict__ vT,    // [bh][dh][l] bf16
    const unsigned short* __restrict__ qpos,  // [bh*L][301] bf16 (scaled 1/8)
    const int* __restrict__ mask,             // [b][q][k] int32/f32-nonzero
    unsigned short* __restrict__ outb)        // [b][l][D] bf16
{
    const int bh = blockIdx.x;                // fast dim -> XCD panel locality
    const int qblk = blockIdx.y;
    const int b = bh >> 4, h = bh & 15;
    const int tid = threadIdx.x;
    const int w = tid >> 6;
    const int lane = tid & 63;
    const int g = lane >> 4;
    const int qc = lane & 15;
    const int gq = qblk * 64 + w * 16 + qc;

    __shared__ alignas(16) unsigned short Qp[64 * NPOS];   // 38528 B
    __shared__ alignas(16) unsigned char Plds[4 * 2048];   //  8192 B
    unsigned char* myP = Plds + w * 2048 + qc * 128;
    const int swz = (qc & 7) << 4;

    // ---- stage qpos slab (contiguous 64*301 bf16), coalesced ----
    {
        const unsigned short* qslab = qpos + ((size_t)bh * LL + (size_t)qblk * 64) * NPOS;
        for (int i = tid; i < (64 * NPOS) / 8; i += 256)   // 2408 short8 chunks
            *reinterpret_cast<short8*>(&Qp[i * 8]) =
                *reinterpret_cast<const short8*>(qslab + (size_t)i * 8);
    }

    const unsigned short* qrow = qbf + ((size_t)bh * LL + gq) * DH;
    const short8 qf0 = *reinterpret_cast<const short8*>(qrow + g * 8);
    const short8 qf1 = *reinterpret_cast<const short8*>(qrow + g * 8 + 32);

    const unsigned short* kb0 = kbf + (size_t)bh * LL * DH;
    const unsigned short* vb0 = vT + (size_t)bh * DH * LL;
    const int* mrp = mask + ((size_t)b * LL + gq) * LL;
    const unsigned short* qpr = &Qp[(w * 16 + qc) * NPOS];

    float mrun = -3.0e38f, lrun = 0.f;
    f32x4 o[4];
#pragma unroll
    for (int m = 0; m < 4; ++m) o[m] = (f32x4){0.f, 0.f, 0.f, 0.f};

    __syncthreads();                          // Qp ready (read-only afterwards)

    for (int kt = 0; kt < LL; kt += 64) {
        f32x4 s[4];
#pragma unroll
        for (int m = 0; m < 4; ++m) s[m] = (f32x4){0.f, 0.f, 0.f, 0.f};
#pragma unroll
        for (int m = 0; m < 4; ++m) {
            const unsigned short* krow = kb0 + (size_t)(kt + m * 16 + qc) * DH + g * 8;
            short8 a0 = *reinterpret_cast<const short8*>(krow);
            short8 a1 = *reinterpret_cast<const short8*>(krow + 32);
            s[m] = __builtin_amdgcn_mfma_f32_16x16x32_bf16(a0, qf0, s[m], 0, 0, 0);
            s[m] = __builtin_amdgcn_mfma_f32_16x16x32_bf16(a1, qf1, s[m], 0, 0, 0);
        }

        float sv[4][4];
        float tmax = -3.0e38f;
#pragma unroll
        for (int m = 0; m < 4; ++m) {
            const int kb = kt + m * 16 + g * 4;
            const int4 mv = *reinterpret_cast<const int4*>(mrp + kb);
#pragma unroll
            for (int r = 0; r < 4; ++r) {
                const int k = kb + r;
                int rel = k - gq;
                rel = rel < -MAXL ? -MAXL : (rel > MAXL ? MAXL : rel);
                int idx = rel + MAXL - 1;
                if (idx < 0) idx += NPOS;      // torch negative-index wraparound
                float x = s[m][r] + b2f(qpr[idx]);   // both pre-scaled by 1/8
                const int mk = (r == 0 ? mv.x : r == 1 ? mv.y : r == 2 ? mv.z : mv.w);
                x = mk ? NEG_INF : x;
                sv[m][r] = x;
                tmax = fmaxf(tmax, x);
            }
        }

        tmax = fmaxf(tmax, __shfl_xor(tmax, 16));
        tmax = fmaxf(tmax, __shfl_xor(tmax, 32));
        const float nm = fmaxf(mrun, tmax);
        const float al = __expf(mrun - nm);
        mrun = nm;
        float ls = 0.f;
#pragma unroll
        for (int m = 0; m < 4; ++m)
#pragma unroll
            for (int r = 0; r < 4; ++r) {
                const float p = __expf(sv[m][r] - nm);
                sv[m][r] = p;
                ls += p;
            }
        ls += __shfl_xor(ls, 16);
        ls += __shfl_xor(ls, 32);
        lrun = lrun * al + ls;
#pragma unroll
        for (int m = 0; m < 4; ++m) o[m] *= al;

#pragma unroll
        for (int m = 0; m < 4; ++m) {
            *reinterpret_cast<unsigned*>(myP + ((32 * m + 8 * g) ^ swz)) = pack2(sv[m][0], sv[m][1]);
            *reinterpret_cast<unsigned*>(myP + ((32 * m + 8 * g + 4) ^ swz)) = pack2(sv[m][2], sv[m][3]);
        }
        const short8 pf0 = *reinterpret_cast<const short8*>(myP + ((16 * g) ^ swz));
        const short8 pf1 = *reinterpret_cast<const short8*>(myP + ((64 + 16 * g) ^ swz));

#pragma unroll
        for (int m = 0; m < 4; ++m) {
            const unsigned short* vrow = vb0 + (size_t)(m * 16 + qc) * LL + kt + g * 8;
            short8 va0 = *reinterpret_cast<const short8*>(vrow);
            short8 va1 = *reinterpret_cast<const short8*>(vrow + 32);
            o[m] = __builtin_amdgcn_mfma_f32_16x16x32_bf16(va0, pf0, o[m], 0, 0, 0);
            o[m] = __builtin_amdgcn_mfma_f32_16x16x32_bf16(va1, pf1, o[m], 0, 0, 0);
        }
    }

    const float inv = 1.f / lrun;
    unsigned short* orow = outb + ((size_t)b * LL + gq) * DD + h * DH;
#pragma unroll
    for (int m = 0; m < 4; ++m)
#pragma unroll
        for (int r = 0; r < 4; ++r)
            orow[m * 16 + g * 4 + r] = f2b(o[m][r] * inv);
}

// ---------------------------------------------------------------------------
// Inputs (dict order): 0 Q, 1 K, 2 V, 3 mask, 4 Wq, 5 bq, 6 Wk, 7 bk,
// 8 Wv, 9 bv, 10 Wo, 11 bo, 12 pos_emb.  Output: [B, L, D] float32.
// Workspace (ushort units): qbf kbf vT Qc Kc Vc (6x4M) + Wqb Wkb Wvb Wob
// (4x1M) + qpos bf16 [65536][301] (39.5 MB) + attnb (4M, peb aliased at its
// start -- pe's last read precedes attn's first write, stream-ordered).
// Total ~103.5 MB (< round-1's 146 MB, known to fit).
// ---------------------------------------------------------------------------
extern "C" void kernel_launch(void* const* d_in, const int* in_sizes, int n_in,
                              void* d_out, int out_size, void* d_ws, size_t ws_size,
                              hipStream_t stream)
{
    const float* Q  = (const float*)d_in[0];
    const float* K  = (const float*)d_in[1];
    const float* V  = (const float*)d_in[2];
    const int* mask = (const int*)d_in[3];
    const float* Wq = (const float*)d_in[4];
    const float* bq = (const float*)d_in[5];
    const float* Wk = (const float*)d_in[6];
    const float* bk = (const float*)d_in[7];
    const float* Wv = (const float*)d_in[8];
    const float* bv = (const float*)d_in[9];
    const float* Wo = (const float*)d_in[10];
    const float* bo = (const float*)d_in[11];
    const float* pe = (const float*)d_in[12];
    float* out = (float*)d_out;

    unsigned short* ws = (unsigned short*)d_ws;
    const size_t NQ = (size_t)BB * HH * LL * DH;       // 4,194,304
    const size_t NW = (size_t)DD * DD;                 // 1,048,576
    unsigned short* qbf = ws;
    unsigned short* kbf = qbf + NQ;
    unsigned short* vT  = kbf + NQ;
    unsigned short* Qc  = vT + NQ;
    unsigned short* Kc  = Qc + NQ;
    unsigned short* Vc  = Kc + NQ;
    unsigned short* Wqb = Vc + NQ;
    unsigned short* Wkb = Wqb + NW;
    unsigned short* Wvb = Wkb + NW;
    unsigned short* Wob = Wvb + NW;
    unsigned short* qpos = Wob + NW;                   // bf16 [65536][301]
    unsigned short* attnb = qpos + (size_t)BB * HH * LL * NPOS;
    unsigned short* peb = attnb;                       // aliased (disjoint lifetime)

    const dim3 blk(256);
    const int M = BB * LL;                             // 4096
    const int NE = (int)NQ, NWE = (int)NW;

    conv_b16<<<dim3(NE / 2048), blk, 0, stream>>>(Q, Qc, NE);
    conv_b16<<<dim3(NE / 2048), blk, 0, stream>>>(K, Kc, NE);
    conv_b16<<<dim3(NE / 2048), blk, 0, stream>>>(V, Vc, NE);
    conv_b16<<<dim3(NWE / 2048), blk, 0, stream>>>(Wq, Wqb, NWE);
    conv_b16<<<dim3(NWE / 2048), blk, 0, stream>>>(Wk, Wkb, NWE);
    conv_b16<<<dim3(NWE / 2048), blk, 0, stream>>>(Wv, Wvb, NWE);
    conv_b16<<<dim3(NWE / 2048), blk, 0, stream>>>(Wo, Wob, NWE);
    conv_b16<<<dim3(10), blk, 0, stream>>>(pe, peb, NPOS * DH);

    gemm_mfma<1, false><<<dim3(16, 32), blk, 0, stream>>>(Qc, Wqb, bq, qbf, M, DD, DD, 0.125f);
    gemm_mfma<1, false><<<dim3(16, 32), blk, 0, stream>>>(Kc, Wkb, bk, kbf, M, DD, DD, 1.0f);
    gemm_mfma<2, false><<<dim3(16, 32), blk, 0, stream>>>(Vc, Wvb, bv, vT, M, DD, DD, 1.0f);
    gemm_mfma<3, true><<<dim3(5, 512), blk, 0, stream>>>(
        qbf, peb, nullptr, qpos, BB * HH * LL, NPOS, DH, 1.0f);
    attn_mfma<<<dim3(BB * HH, LL / 64), blk, 0, stream>>>(qbf, kbf, vT, qpos, mask, attnb);
    gemm_mfma<0, false><<<dim3(16, 32), blk, 0, stream>>>(attnb, Wob, bo, out, M, DD, DD, 1.0f);
}

// Round 9
// 320.547 us; speedup vs baseline: 1.1646x; 1.1646x over previous
//
#include <hip/hip_runtime.h>
#include <hip/hip_bf16.h>

// Problem constants (B=4, L=1024, D=1024, H=16, Dh=64, MAX_LEN=150)
#define BB 4
#define LL 1024
#define DD 1024
#define HH 16
#define DH 64
#define NPOS 301      // 2*MAX_LEN+1
#define MAXL 150
#define NEG_INF -1e30f

typedef __attribute__((ext_vector_type(4))) float f32x4;
typedef __attribute__((ext_vector_type(8))) short short8;

__device__ inline unsigned short f2b(float x) {
    __hip_bfloat16 h = __float2bfloat16(x);
    return *reinterpret_cast<unsigned short*>(&h);
}
__device__ inline unsigned pack2(float a, float b) {
    return (unsigned)f2b(a) | ((unsigned)f2b(b) << 16);
}
__device__ inline float b2f(unsigned short u) {
    return __uint_as_float((unsigned)u << 16);
}

// ---------------------------------------------------------------------------
// f32 -> bf16 conversion, 8 elems/thread
// ---------------------------------------------------------------------------
__global__ __launch_bounds__(256) void conv_b16(const float* __restrict__ in,
                                                unsigned short* __restrict__ out, int n)
{
    const size_t i = ((size_t)blockIdx.x * 256 + threadIdx.x) * 8;
    if (i >= (size_t)n) return;
    float4 a = *reinterpret_cast<const float4*>(in + i);
    float4 b = *reinterpret_cast<const float4*>(in + i + 4);
    ushort4 u0 = {f2b(a.x), f2b(a.y), f2b(a.z), f2b(a.w)};
    ushort4 u1 = {f2b(b.x), f2b(b.y), f2b(b.z), f2b(b.w)};
    *reinterpret_cast<ushort4*>(out + i) = u0;
    *reinterpret_cast<ushort4*>(out + i + 4) = u1;
}

// ---------------------------------------------------------------------------
// bf16 MFMA GEMM: C = (A @ W^T + bias) * oscale.  (validated rounds 7-8)
// Tile 128(M) x 64(N), BK=32, 4 waves (2x2), wave owns 64x32; padded-LDS
// reg-staged; fragment mapping validated rounds 6-8.
// EPI 0: f32 [M][N]                  (final projection)
// EPI 1: bf16 permuted [bh][l][dh]   (q/k projections)
// EPI 2: bf16 transposed [bh][dh][l] (v projection -> V^T direct)
// EPI 3: bf16 plain [M][N]           (qpos table, GN guards N=301)
// ---------------------------------------------------------------------------
template <int EPI, bool GN>
__global__ __launch_bounds__(256) void gemm_mfma(
    const unsigned short* __restrict__ A, const unsigned short* __restrict__ W,
    const float* __restrict__ bias, void* __restrict__ Cout,
    int M, int N, int K, float oscale)
{
    __shared__ alignas(16) unsigned short As[128 * 40];
    __shared__ alignas(16) unsigned short Bs[64 * 40];
    const int tid = threadIdx.x;
    const int w = tid >> 6, lane = tid & 63;
    const int wr = w >> 1, wc = w & 1;
    const int g = lane >> 4, fr = lane & 15;
    const int m0 = blockIdx.y * 128;
    const int n0 = blockIdx.x * 64;

    f32x4 acc[4][2];
#pragma unroll
    for (int i = 0; i < 4; ++i)
#pragma unroll
        for (int j = 0; j < 2; ++j) acc[i][j] = (f32x4){0.f, 0.f, 0.f, 0.f};

    const int arow0 = tid >> 2, agg = tid & 3;
    for (int k0 = 0; k0 < K; k0 += 32) {
        {
            short8 v0 = *reinterpret_cast<const short8*>(
                A + (size_t)(m0 + arow0) * K + k0 + agg * 8);
            short8 v1 = *reinterpret_cast<const short8*>(
                A + (size_t)(m0 + arow0 + 64) * K + k0 + agg * 8);
            int nr = n0 + arow0;
            if (GN && nr >= N) nr = N - 1;
            short8 bv = *reinterpret_cast<const short8*>(
                W + (size_t)nr * K + k0 + agg * 8);
            *reinterpret_cast<short8*>(&As[arow0 * 40 + agg * 8]) = v0;
            *reinterpret_cast<short8*>(&As[(arow0 + 64) * 40 + agg * 8]) = v1;
            *reinterpret_cast<short8*>(&Bs[arow0 * 40 + agg * 8]) = bv;
        }
        __syncthreads();
        short8 af[4], bf[2];
#pragma unroll
        for (int i = 0; i < 4; ++i)
            af[i] = *reinterpret_cast<const short8*>(
                &As[(wr * 64 + i * 16 + fr) * 40 + g * 8]);
#pragma unroll
        for (int j = 0; j < 2; ++j)
            bf[j] = *reinterpret_cast<const short8*>(
                &Bs[(wc * 32 + j * 16 + fr) * 40 + g * 8]);
#pragma unroll
        for (int i = 0; i < 4; ++i)
#pragma unroll
            for (int j = 0; j < 2; ++j)
                acc[i][j] = __builtin_amdgcn_mfma_f32_16x16x32_bf16(
                    af[i], bf[j], acc[i][j], 0, 0, 0);
        __syncthreads();
    }

#pragma unroll
    for (int i = 0; i < 4; ++i) {
#pragma unroll
        for (int j = 0; j < 2; ++j) {
#pragma unroll
            for (int r = 0; r < 4; ++r) {
                const int row = m0 + wr * 64 + i * 16 + g * 4 + r;
                const int col = n0 + wc * 32 + j * 16 + fr;
                if (GN && col >= N) continue;
                const float val = (acc[i][j][r] + (bias ? bias[col] : 0.f)) * oscale;
                if (EPI == 0) {
                    ((float*)Cout)[(size_t)row * N + col] = val;
                } else if (EPI == 1) {
                    const int b = row >> 10, l = row & 1023, hh = col >> 6, dh = col & 63;
                    ((unsigned short*)Cout)[(((size_t)(b * HH + hh)) * LL + l) * DH + dh] = f2b(val);
                } else if (EPI == 2) {
                    const int b = row >> 10, l = row & 1023, hh = col >> 6, dh = col & 63;
                    ((unsigned short*)Cout)[(((size_t)(b * HH + hh)) * DH + dh) * LL + l] = f2b(val);
                } else {
                    ((unsigned short*)Cout)[(size_t)row * N + col] = f2b(val);
                }
            }
        }
    }
}

// ---------------------------------------------------------------------------
// MFMA attention (math validated rounds 6-8). NEW this round:
//  * TQ=32: block = 128 threads (2 waves x 16 q-rows), grid (64 bh, 32 qblk)
//    = 2048 blocks -> ~8 blocks/CU, double r7's resident waves. LDS = 4 KB.
//  * Banded qpos gather, NO LDS slab: idx = clip(k-q)+149 saturates to
//    row[300] (left) / row[299] (right) for |k-q|>150 -- 71% of pairs.
//    Hoist both constants into registers; fully-saturated 4-runs do ZERO
//    loads; in-band runs do scalar u16 reads of the once-streamed bf16 table.
//    Same values as r8's LDS gather -> bit-identical output.
// ---------------------------------------------------------------------------
__global__ __launch_bounds__(128) void attn_mfma(
    const unsigned short* __restrict__ qbf,   // [bh][l][dh] bf16 (scaled 1/8)
    const unsigned short* __restrict__ kbf,   // [bh][l][dh] bf16
    const unsigned short* __restrict__ vT,    // [bh][dh][l] bf16
    const unsigned short* __restrict__ qpos,  // [bh*L][301] bf16 (scaled 1/8)
    const int* __restrict__ mask,             // [b][q][k] int32/f32-nonzero
    unsigned short* __restrict__ outb)        // [b][l][D] bf16
{
    const int bh = blockIdx.x;                // fast dim -> XCD panel locality
    const int qblk = blockIdx.y;
    const int b = bh >> 4, h = bh & 15;
    const int tid = threadIdx.x;
    const int w = tid >> 6;                   // 0..1
    const int lane = tid & 63;
    const int g = lane >> 4;
    const int qc = lane & 15;
    const int gq = qblk * 32 + w * 16 + qc;

    __shared__ alignas(16) unsigned char Plds[2 * 2048];
    unsigned char* myP = Plds + w * 2048 + qc * 128;
    const int swz = (qc & 7) << 4;

    const unsigned short* qrow = qbf + ((size_t)bh * LL + gq) * DH;
    const short8 qf0 = *reinterpret_cast<const short8*>(qrow + g * 8);
    const short8 qf1 = *reinterpret_cast<const short8*>(qrow + g * 8 + 32);

    const unsigned short* kb0 = kbf + (size_t)bh * LL * DH;
    const unsigned short* vb0 = vT + (size_t)bh * DH * LL;
    const int* mrp = mask + ((size_t)b * LL + gq) * LL;
    const unsigned short* qpr = qpos + ((size_t)bh * LL + gq) * NPOS;
    const float c_left = b2f(qpr[300]);       // rel <= -150
    const float c_right = b2f(qpr[299]);      // rel >= +150

    float mrun = -3.0e38f, lrun = 0.f;
    f32x4 o[4];
#pragma unroll
    for (int m = 0; m < 4; ++m) o[m] = (f32x4){0.f, 0.f, 0.f, 0.f};

    for (int kt = 0; kt < LL; kt += 64) {
        f32x4 s[4];
#pragma unroll
        for (int m = 0; m < 4; ++m) s[m] = (f32x4){0.f, 0.f, 0.f, 0.f};
#pragma unroll
        for (int m = 0; m < 4; ++m) {
            const unsigned short* krow = kb0 + (size_t)(kt + m * 16 + qc) * DH + g * 8;
            short8 a0 = *reinterpret_cast<const short8*>(krow);
            short8 a1 = *reinterpret_cast<const short8*>(krow + 32);
            s[m] = __builtin_amdgcn_mfma_f32_16x16x32_bf16(a0, qf0, s[m], 0, 0, 0);
            s[m] = __builtin_amdgcn_mfma_f32_16x16x32_bf16(a1, qf1, s[m], 0, 0, 0);
        }

        float sv[4][4];
        float tmax = -3.0e38f;
#pragma unroll
        for (int m = 0; m < 4; ++m) {
            const int kb = kt + m * 16 + g * 4;
            const int4 mv = *reinterpret_cast<const int4*>(mrp + kb);
            // banded relative-position values for k = kb..kb+3
            const int p0 = kb - gq + 149;     // unclipped idx of r=0
            float rp0, rp1, rp2, rp3;
            if (p0 > 299) {                   // whole run right-saturated
                rp0 = rp1 = rp2 = rp3 = c_right;
            } else if (p0 < -3) {             // whole run left-saturated
                rp0 = rp1 = rp2 = rp3 = c_left;
            } else {                          // in band (or straddling edge)
                int i0 = p0 < 0 ? 300 : p0;
                int i1 = p0 + 1 < 0 ? 300 : (p0 + 1 > 299 ? 299 : p0 + 1);
                int i2 = p0 + 2 < 0 ? 300 : (p0 + 2 > 299 ? 299 : p0 + 2);
                int i3 = p0 + 3 > 299 ? 299 : p0 + 3;
                rp0 = b2f(qpr[i0]); rp1 = b2f(qpr[i1]);
                rp2 = b2f(qpr[i2]); rp3 = b2f(qpr[i3]);
            }
#pragma unroll
            for (int r = 0; r < 4; ++r) {
                const float rp = (r == 0 ? rp0 : r == 1 ? rp1 : r == 2 ? rp2 : rp3);
                float x = s[m][r] + rp;       // both pre-scaled by 1/8
                const int mk = (r == 0 ? mv.x : r == 1 ? mv.y : r == 2 ? mv.z : mv.w);
                x = mk ? NEG_INF : x;
                sv[m][r] = x;
                tmax = fmaxf(tmax, x);
            }
        }

        tmax = fmaxf(tmax, __shfl_xor(tmax, 16));
        tmax = fmaxf(tmax, __shfl_xor(tmax, 32));
        const float nm = fmaxf(mrun, tmax);
        const float al = __expf(mrun - nm);
        mrun = nm;
        float ls = 0.f;
#pragma unroll
        for (int m = 0; m < 4; ++m)
#pragma unroll
            for (int r = 0; r < 4; ++r) {
                const float p = __expf(sv[m][r] - nm);
                sv[m][r] = p;
                ls += p;
            }
        ls += __shfl_xor(ls, 16);
        ls += __shfl_xor(ls, 32);
        lrun = lrun * al + ls;
#pragma unroll
        for (int m = 0; m < 4; ++m) o[m] *= al;

#pragma unroll
        for (int m = 0; m < 4; ++m) {
            *reinterpret_cast<unsigned*>(myP + ((32 * m + 8 * g) ^ swz)) = pack2(sv[m][0], sv[m][1]);
            *reinterpret_cast<unsigned*>(myP + ((32 * m + 8 * g + 4) ^ swz)) = pack2(sv[m][2], sv[m][3]);
        }
        const short8 pf0 = *reinterpret_cast<const short8*>(myP + ((16 * g) ^ swz));
        const short8 pf1 = *reinterpret_cast<const short8*>(myP + ((64 + 16 * g) ^ swz));

#pragma unroll
        for (int m = 0; m < 4; ++m) {
            const unsigned short* vrow = vb0 + (size_t)(m * 16 + qc) * LL + kt + g * 8;
            short8 va0 = *reinterpret_cast<const short8*>(vrow);
            short8 va1 = *reinterpret_cast<const short8*>(vrow + 32);
            o[m] = __builtin_amdgcn_mfma_f32_16x16x32_bf16(va0, pf0, o[m], 0, 0, 0);
            o[m] = __builtin_amdgcn_mfma_f32_16x16x32_bf16(va1, pf1, o[m], 0, 0, 0);
        }
    }

    const float inv = 1.f / lrun;
    unsigned short* orow = outb + ((size_t)b * LL + gq) * DD + h * DH;
#pragma unroll
    for (int m = 0; m < 4; ++m)
#pragma unroll
        for (int r = 0; r < 4; ++r)
            orow[m * 16 + g * 4 + r] = f2b(o[m][r] * inv);
}

// ---------------------------------------------------------------------------
// Inputs (dict order): 0 Q, 1 K, 2 V, 3 mask, 4 Wq, 5 bq, 6 Wk, 7 bk,
// 8 Wv, 9 bv, 10 Wo, 11 bo, 12 pos_emb.  Output: [B, L, D] float32.
// Workspace (ushort units): qbf kbf vT Qc Kc Vc (6x4M) + Wqb Wkb Wvb Wob
// (4x1M) + qpos bf16 [65536][301] (39.5 MB) + attnb (4M, peb aliased at its
// start -- pe's last read precedes attn's first write, stream-ordered).
// Total ~103.5 MB (fits; round-1's 146 MB ran clean).
// ---------------------------------------------------------------------------
extern "C" void kernel_launch(void* const* d_in, const int* in_sizes, int n_in,
                              void* d_out, int out_size, void* d_ws, size_t ws_size,
                              hipStream_t stream)
{
    const float* Q  = (const float*)d_in[0];
    const float* K  = (const float*)d_in[1];
    const float* V  = (const float*)d_in[2];
    const int* mask = (const int*)d_in[3];
    const float* Wq = (const float*)d_in[4];
    const float* bq = (const float*)d_in[5];
    const float* Wk = (const float*)d_in[6];
    const float* bk = (const float*)d_in[7];
    const float* Wv = (const float*)d_in[8];
    const float* bv = (const float*)d_in[9];
    const float* Wo = (const float*)d_in[10];
    const float* bo = (const float*)d_in[11];
    const float* pe = (const float*)d_in[12];
    float* out = (float*)d_out;

    unsigned short* ws = (unsigned short*)d_ws;
    const size_t NQ = (size_t)BB * HH * LL * DH;       // 4,194,304
    const size_t NW = (size_t)DD * DD;                 // 1,048,576
    unsigned short* qbf = ws;
    unsigned short* kbf = qbf + NQ;
    unsigned short* vT  = kbf + NQ;
    unsigned short* Qc  = vT + NQ;
    unsigned short* Kc  = Qc + NQ;
    unsigned short* Vc  = Kc + NQ;
    unsigned short* Wqb = Vc + NQ;
    unsigned short* Wkb = Wqb + NW;
    unsigned short* Wvb = Wkb + NW;
    unsigned short* Wob = Wvb + NW;
    unsigned short* qpos = Wob + NW;                   // bf16 [65536][301]
    unsigned short* attnb = qpos + (size_t)BB * HH * LL * NPOS;
    unsigned short* peb = attnb;                       // aliased (disjoint lifetime)

    const dim3 blk(256);
    const int M = BB * LL;                             // 4096
    const int NE = (int)NQ, NWE = (int)NW;

    conv_b16<<<dim3(NE / 2048), blk, 0, stream>>>(Q, Qc, NE);
    conv_b16<<<dim3(NE / 2048), blk, 0, stream>>>(K, Kc, NE);
    conv_b16<<<dim3(NE / 2048), blk, 0, stream>>>(V, Vc, NE);
    conv_b16<<<dim3(NWE / 2048), blk, 0, stream>>>(Wq, Wqb, NWE);
    conv_b16<<<dim3(NWE / 2048), blk, 0, stream>>>(Wk, Wkb, NWE);
    conv_b16<<<dim3(NWE / 2048), blk, 0, stream>>>(Wv, Wvb, NWE);
    conv_b16<<<dim3(NWE / 2048), blk, 0, stream>>>(Wo, Wob, NWE);
    conv_b16<<<dim3(10), blk, 0, stream>>>(pe, peb, NPOS * DH);

    gemm_mfma<1, false><<<dim3(16, 32), blk, 0, stream>>>(Qc, Wqb, bq, qbf, M, DD, DD, 0.125f);
    gemm_mfma<1, false><<<dim3(16, 32), blk, 0, stream>>>(Kc, Wkb, bk, kbf, M, DD, DD, 1.0f);
    gemm_mfma<2, false><<<dim3(16, 32), blk, 0, stream>>>(Vc, Wvb, bv, vT, M, DD, DD, 1.0f);
    gemm_mfma<3, true><<<dim3(5, 512), blk, 0, stream>>>(
        qbf, peb, nullptr, qpos, BB * HH * LL, NPOS, DH, 1.0f);
    attn_mfma<<<dim3(BB * HH, LL / 32), dim3(128), 0, stream>>>(
        qbf, kbf, vT, qpos, mask, attnb);
    gemm_mfma<0, false><<<dim3(16, 32), blk, 0, stream>>>(attnb, Wob, bo, out, M, DD, DD, 1.0f);
}